// Round 1
// baseline (448.989 us; speedup 1.0000x reference)
//
#include <hip/hip_runtime.h>

// EMA: y[b,c,t] = g*y[b,c,t-1] + (1-g)*x[b,c,t],  y[-1]=0, g = weight[c]
// Shapes: B=8, C=512, T=16384 (fp32). 4096 independent rows of length 16384.
//
// Barrier-free structure: each WAVE owns one full row (4 rows per 256-thread
// block). Per iteration a wave processes a contiguous 256-elem window
// (float4/lane, coalesced 1KB/instr). Exact parallel scan:
//   per-lane 4-elem local scan -> Kogge-Stone wave scan of carries with
//   uniform factor g^4 -> broadcast of lane63 value for the cross-window
//   carry (factor g^256). No __syncthreads, no LDS -> no vmcnt-drain points,
//   so the depth-1 load prefetch stays in flight across iterations.

#define B_ 8
#define C_ 512
#define T_ 16384
#define WIN 256             // elements per iteration window (64 lanes * 4)
#define NITER (T_ / WIN)    // 64

__global__ __launch_bounds__(256)
void ema_scan_kernel(const float* __restrict__ x,
                     const float* __restrict__ weight,
                     float* __restrict__ out) {
    const int tid  = threadIdx.x;
    const int lane = tid & 63;
    const int w    = tid >> 6;                 // wave id 0..3
    const int row  = (blockIdx.x << 2) + w;    // 0..4095  (b*C + c)
    const int c    = row & (C_ - 1);

    const float g     = weight[c];
    const float onemg = 1.0f - g;

    // powers of g: f[k] = g^(4*2^k)  (g^4, g^8, g^16, g^32, g^64, g^128)
    const float g2 = g * g;
    const float g4 = g2 * g2;
    float f[6];
    f[0] = g4;
    #pragma unroll
    for (int k = 1; k < 6; ++k) f[k] = f[k - 1] * f[k - 1];
    const float g256 = f[5] * f[5];            // window carry factor
    // lane_factor = g^(4*lane) via binary expansion
    float lane_factor = 1.0f;
    #pragma unroll
    for (int k = 0; k < 6; ++k)
        if (lane & (1 << k)) lane_factor *= f[k];

    const float4* __restrict__ xrow = (const float4*)(x   + (size_t)row * T_);
    float4*       __restrict__ orow = (float4*)      (out + (size_t)row * T_);

    float carry = 0.0f;                        // y value just before window
    float4 X = xrow[lane];                     // prefetch window 0

    #pragma unroll 2
    for (int it = 0; it < NITER; ++it) {
        // prefetch next window (last iter re-reads its own window; L2-hit)
        const int nit = (it + 1 < NITER) ? (it + 1) : it;
        const float4 Xn = xrow[nit * 64 + lane];

        // local 4-element scan (zero carry-in)
        const float z0 = onemg * X.x;
        const float z1 = fmaf(g, z0, onemg * X.y);
        const float z2 = fmaf(g, z1, onemg * X.z);
        const float z3 = fmaf(g, z2, onemg * X.w);

        // Kogge-Stone inclusive scan of per-lane carries across the wave:
        // v_l = sum_{m<=l} (g^4)^(l-m) * z3_m
        float v = z3;
        #pragma unroll
        for (int k = 0; k < 6; ++k) {
            const float t = __shfl_up(v, 1 << k, 64);
            if (lane >= (1 << k)) v = fmaf(f[k], t, v);
        }
        // exclusive value: y at end of previous lane's chunk (window-rel.)
        float e = __shfl_up(v, 1, 64);
        if (lane == 0) e = 0.0f;

        // window-end value (window-relative, zero init) for the carry chain
        const float v63 = __shfl(v, 63, 64);

        // absolute carry just before this thread's 4 elements
        const float cth = fmaf(lane_factor, carry, e);

        float gp = g * cth;
        float4 Y;
        Y.x = z0 + gp; gp *= g;
        Y.y = z1 + gp; gp *= g;
        Y.z = z2 + gp; gp *= g;
        Y.w = z3 + gp;
        orow[it * 64 + lane] = Y;

        carry = fmaf(g256, carry, v63);        // exact cross-window carry
        X = Xn;
    }
}

extern "C" void kernel_launch(void* const* d_in, const int* in_sizes, int n_in,
                              void* d_out, int out_size, void* d_ws, size_t ws_size,
                              hipStream_t stream) {
    const float* x      = (const float*)d_in[0];
    const float* weight = (const float*)d_in[1];
    float* out          = (float*)d_out;
    ema_scan_kernel<<<(B_ * C_) / 4, 256, 0, stream>>>(x, weight, out);
}

// Round 2
// 437.288 us; speedup vs baseline: 1.0268x; 1.0268x over previous
//
#include <hip/hip_runtime.h>

// EMA: y[b,c,t] = g*y[b,c,t-1] + (1-g)*x[b,c,t],  y[-1]=0, g = weight[c]
// Shapes: B=8, C=512, T=16384 (fp32). 4096 independent rows of length 16384.
//
// Structure: each WAVE owns a 4096-elem SEGMENT (4 segments/row). 16384
// waves total = 64 waves/CU requested -> full occupancy (round-1's 16
// waves/CU was the regression cause: too few in-flight loads).
// Barrier-free, LDS-free: Kogge-Stone shuffle scan within the wave.
//
// Cross-segment carry: y[s-1] = sum_{k<256} g^k (1-g) x[s-1-k]  +  g^256*y[s-257].
// g^256 ~ 2e-12 (g=0.9), far below fp32 rounding of the result, so a
// 256-elem warmup dot-product (1 float4/lane + butterfly reduce) yields the
// incoming carry exactly to rounding. Extra read traffic: ~2%.
//
// Loads are software-pipelined to depth 2 (2 KB in flight per wave).

#define B_ 8
#define C_ 512
#define T_ 16384
#define SEGS 4
#define SEGV (T_ / SEGS / 4)   // 1024 float4 per segment
#define NITER (SEGV / 64)      // 16 iterations (64 float4 / wave / iter)

__global__ __launch_bounds__(256)
void ema_scan_kernel(const float* __restrict__ x,
                     const float* __restrict__ weight,
                     float* __restrict__ out) {
    const int tid  = threadIdx.x;
    const int lane = tid & 63;
    const int w    = tid >> 6;                  // wave id in block
    const int gid  = (blockIdx.x << 2) + w;     // 0..16383
    const int row  = gid >> 2;                  // 0..4095  (b*C + c)
    const int seg  = gid & 3;                   // 0..3
    const int c    = row & (C_ - 1);

    const float g     = weight[c];
    const float onemg = 1.0f - g;

    // powers of g: f[k] = g^(4*2^k)  (g^4 .. g^128)
    const float g2 = g * g;
    const float g4 = g2 * g2;
    float f[6];
    f[0] = g4;
    #pragma unroll
    for (int k = 1; k < 6; ++k) f[k] = f[k - 1] * f[k - 1];
    const float g256 = f[5] * f[5];             // window carry factor
    // lane_factor = g^(4*lane); rev_factor = g^(4*(63-lane))
    float lane_factor = 1.0f, rev_factor = 1.0f;
    #pragma unroll
    for (int k = 0; k < 6; ++k) {
        if (lane & (1 << k))        lane_factor *= f[k];
        if ((lane ^ 63) & (1 << k)) rev_factor  *= f[k];
    }

    const float4* __restrict__ xrow = (const float4*)(x   + (size_t)row * T_);
    float4*       __restrict__ orow = (float4*)      (out + (size_t)row * T_);

    const int segv0 = seg * SEGV;               // first float4 index of segment

    // ---- warmup: incoming carry from the 256 elems before the segment ----
    float carry = 0.0f;
    if (seg != 0) {
        const float4 Xw = xrow[segv0 - 64 + lane];
        // p = g^3*Xw.x + g^2*Xw.y + g*Xw.z + Xw.w
        const float p = fmaf(g, fmaf(g, fmaf(g, Xw.x, Xw.y), Xw.z), Xw.w);
        float t = rev_factor * p;
        #pragma unroll
        for (int k = 0; k < 6; ++k)
            t += __shfl_xor(t, 1 << k, 64);     // butterfly: all lanes get sum
        carry = onemg * t;                      // = y[segment_start - 1]
    }

    // ---- depth-2 pipelined main scan over the segment ----
    float4 X0 = xrow[segv0 + lane];
    float4 X1 = xrow[segv0 + 64 + lane];

    #pragma unroll 2
    for (int it = 0; it < NITER; ++it) {
        const int pf = (it + 2 < NITER) ? (it + 2) : (NITER - 1);
        const float4 Xn = xrow[segv0 + pf * 64 + lane];

        // local 4-element scan (zero carry-in)
        const float z0 = onemg * X0.x;
        const float z1 = fmaf(g, z0, onemg * X0.y);
        const float z2 = fmaf(g, z1, onemg * X0.z);
        const float z3 = fmaf(g, z2, onemg * X0.w);

        // Kogge-Stone inclusive scan of per-lane carries (factor g^4)
        float v = z3;
        #pragma unroll
        for (int k = 0; k < 6; ++k) {
            const float t = __shfl_up(v, 1 << k, 64);
            if (lane >= (1 << k)) v = fmaf(f[k], t, v);
        }
        // exclusive value: window-relative y at end of previous lane's chunk
        float e = __shfl_up(v, 1, 64);
        if (lane == 0) e = 0.0f;
        const float v63 = __shfl(v, 63, 64);    // window-end (window-relative)

        // absolute carry just before this thread's 4 elements
        const float cth = fmaf(lane_factor, carry, e);

        float gp = g * cth;
        float4 Y;
        Y.x = z0 + gp; gp *= g;
        Y.y = z1 + gp; gp *= g;
        Y.z = z2 + gp; gp *= g;
        Y.w = z3 + gp;
        orow[segv0 + it * 64 + lane] = Y;

        carry = fmaf(g256, carry, v63);         // exact cross-window carry
        X0 = X1; X1 = Xn;
    }
}

extern "C" void kernel_launch(void* const* d_in, const int* in_sizes, int n_in,
                              void* d_out, int out_size, void* d_ws, size_t ws_size,
                              hipStream_t stream) {
    const float* x      = (const float*)d_in[0];
    const float* weight = (const float*)d_in[1];
    float* out          = (float*)d_out;
    ema_scan_kernel<<<(B_ * C_ * SEGS) / 4, 256, 0, stream>>>(x, weight, out);
}

// Round 4
// 429.856 us; speedup vs baseline: 1.0445x; 1.0173x over previous
//
#include <hip/hip_runtime.h>

// EMA: y[b,c,t] = g*y[b,c,t-1] + (1-g)*x[b,c,t],  y[-1]=0, g = weight[c]
// Shapes: B=8, C=512, T=16384 (fp32). 4096 independent rows of length 16384.
//
// Each WAVE owns a 4096-elem SEGMENT (4 segments/row, 16384 waves -> full
// occupancy). Barrier-free, LDS-free. Per iteration a wave processes TWO
// independent 256-elem half-windows (512 elems, 2 coalesced 16B/lane):
// the two Kogge-Stone shuffle chains interleave (ILP=2 on the DS pipe),
// halving exposed shuffle latency per byte, and the serial cross-iteration
// carry chain is half as long as the 256-elem-window version.
//
// Cross-segment carry: y[s-1] = sum_{k<256} g^k (1-g) x[s-1-k] + g^256*y[s-257];
// g^256 ~ 2e-12 << fp32 rounding, so a 256-elem warmup dot product gives the
// incoming carry exactly to rounding (~2% extra read).
//
// x/out are touched exactly once -> nontemporal loads/stores (no L2 thrash).
// NOTE: __builtin_nontemporal_* requires clang vector types, not
// HIP_vector_type<float,4> -> use ext_vector_type(4) float.

#define B_ 8
#define C_ 512
#define T_ 16384
#define SEGS 4
#define SEGV (T_ / SEGS / 4)    // 1024 float4 per segment
#define NITER (SEGV / 128)      // 8 iterations (128 float4 / wave / iter)

typedef float f4 __attribute__((ext_vector_type(4)));

__global__ __launch_bounds__(256)
void ema_scan_kernel(const float* __restrict__ x,
                     const float* __restrict__ weight,
                     float* __restrict__ out) {
    const int tid  = threadIdx.x;
    const int lane = tid & 63;
    const int w    = tid >> 6;                  // wave id in block
    const int gid  = (blockIdx.x << 2) + w;     // 0..16383
    const int row  = gid >> 2;                  // 0..4095  (b*C + c)
    const int seg  = gid & 3;                   // 0..3
    const int c    = row & (C_ - 1);

    const float g     = weight[c];
    const float onemg = 1.0f - g;

    // powers of g: f[k] = g^(4*2^k)  (g^4 .. g^128)
    const float g2 = g * g;
    const float g4 = g2 * g2;
    float f[6];
    f[0] = g4;
    #pragma unroll
    for (int k = 1; k < 6; ++k) f[k] = f[k - 1] * f[k - 1];
    const float g256 = f[5] * f[5];             // half-window carry factor
    // lane_factor = g^(4*lane); rev_factor = g^(4*(63-lane))
    float lane_factor = 1.0f, rev_factor = 1.0f;
    #pragma unroll
    for (int k = 0; k < 6; ++k) {
        if (lane & (1 << k))        lane_factor *= f[k];
        if ((lane ^ 63) & (1 << k)) rev_factor  *= f[k];
    }

    const f4* __restrict__ xrow = (const f4*)(x   + (size_t)row * T_);
    f4*       __restrict__ orow = (f4*)      (out + (size_t)row * T_);

    const int segv0 = seg * SEGV;               // first float4 index of segment

    // ---- warmup: incoming carry from the 256 elems before the segment ----
    float carry = 0.0f;
    if (seg != 0) {
        const f4 Xw = __builtin_nontemporal_load(&xrow[segv0 - 64 + lane]);
        // p = g^3*Xw.x + g^2*Xw.y + g*Xw.z + Xw.w
        const float p = fmaf(g, fmaf(g, fmaf(g, Xw.x, Xw.y), Xw.z), Xw.w);
        float t = rev_factor * p;
        #pragma unroll
        for (int k = 0; k < 6; ++k)
            t += __shfl_xor(t, 1 << k, 64);     // butterfly: all lanes get sum
        carry = onemg * t;                      // = y[segment_start - 1]
    }

    // ---- depth-2 pipelined main scan, 512 elems (two half-windows) / iter ----
    f4 XA0 = __builtin_nontemporal_load(&xrow[segv0 + lane]);
    f4 XB0 = __builtin_nontemporal_load(&xrow[segv0 + 64 + lane]);
    f4 XA1 = __builtin_nontemporal_load(&xrow[segv0 + 128 + lane]);
    f4 XB1 = __builtin_nontemporal_load(&xrow[segv0 + 192 + lane]);

    #pragma unroll 2
    for (int it = 0; it < NITER; ++it) {
        const int pf = (it + 2 < NITER) ? (it + 2) : (NITER - 1);
        const f4 XAn = __builtin_nontemporal_load(&xrow[segv0 + pf * 128 + lane]);
        const f4 XBn = __builtin_nontemporal_load(&xrow[segv0 + pf * 128 + 64 + lane]);

        // local 4-element scans (zero carry-in), two independent chains
        const float a0 = onemg * XA0.x;
        const float b0 = onemg * XB0.x;
        const float a1 = fmaf(g, a0, onemg * XA0.y);
        const float b1 = fmaf(g, b0, onemg * XB0.y);
        const float a2 = fmaf(g, a1, onemg * XA0.z);
        const float b2 = fmaf(g, b1, onemg * XB0.z);
        const float a3 = fmaf(g, a2, onemg * XA0.w);
        const float b3 = fmaf(g, b2, onemg * XB0.w);

        // Kogge-Stone inclusive scans of per-lane carries (factor g^4), ILP=2
        float vA = a3, vB = b3;
        #pragma unroll
        for (int k = 0; k < 6; ++k) {
            const float tA = __shfl_up(vA, 1 << k, 64);
            const float tB = __shfl_up(vB, 1 << k, 64);
            if (lane >= (1 << k)) {
                vA = fmaf(f[k], tA, vA);
                vB = fmaf(f[k], tB, vB);
            }
        }
        float eA = __shfl_up(vA, 1, 64);
        float eB = __shfl_up(vB, 1, 64);
        if (lane == 0) { eA = 0.0f; eB = 0.0f; }
        const float vA63 = __shfl(vA, 63, 64);
        const float vB63 = __shfl(vB, 63, 64);

        // absolute carries just before this thread's elements, each half
        const float cA  = fmaf(lane_factor, carry, eA);
        const float mid = fmaf(g256, carry, vA63);       // y before B-half
        const float cB  = fmaf(lane_factor, mid, eB);

        float gpA = g * cA;
        float gpB = g * cB;
        f4 YA, YB;
        YA.x = a0 + gpA; gpA *= g;
        YB.x = b0 + gpB; gpB *= g;
        YA.y = a1 + gpA; gpA *= g;
        YB.y = b1 + gpB; gpB *= g;
        YA.z = a2 + gpA; gpA *= g;
        YB.z = b2 + gpB; gpB *= g;
        YA.w = a3 + gpA;
        YB.w = b3 + gpB;
        __builtin_nontemporal_store(YA, &orow[segv0 + it * 128 + lane]);
        __builtin_nontemporal_store(YB, &orow[segv0 + it * 128 + 64 + lane]);

        carry = fmaf(g256, mid, vB63);          // exact cross-window carry
        XA0 = XA1; XB0 = XB1; XA1 = XAn; XB1 = XBn;
    }
}

extern "C" void kernel_launch(void* const* d_in, const int* in_sizes, int n_in,
                              void* d_out, int out_size, void* d_ws, size_t ws_size,
                              hipStream_t stream) {
    const float* x      = (const float*)d_in[0];
    const float* weight = (const float*)d_in[1];
    float* out          = (float*)d_out;
    ema_scan_kernel<<<(B_ * C_ * SEGS) / 4, 256, 0, stream>>>(x, weight, out);
}

// Round 5
// 425.370 us; speedup vs baseline: 1.0555x; 1.0105x over previous
//
#include <hip/hip_runtime.h>

// EMA: y[b,c,t] = g*y[b,c,t-1] + (1-g)*x[b,c,t],  y[-1]=0, g = weight[c]
// Shapes: B=8, C=512, T=16384 (fp32). 4096 independent rows of length 16384.
//
// Each WAVE owns a 4096-elem SEGMENT (4 segments/row, 16384 waves -> full
// occupancy). Barrier-free, LDS-free. Per iteration a wave processes TWO
// independent 256-elem half-windows (512 elems, 2 coalesced 16B/lane):
// the two Kogge-Stone shuffle chains interleave (ILP=2 on the DS pipe).
//
// Cross-segment carry: y[s-1] = sum_{k<256} g^k (1-g) x[s-1-k] + g^256*y[s-257];
// g^256 ~ 2e-12 << fp32 rounding, so a 256-elem warmup dot product gives the
// incoming carry exactly to rounding (~2% extra read).
//
// x/out are touched exactly once -> nontemporal loads/stores (no L2 thrash).
// Round-5 fix: prefetch is GUARDED (uniform branch) instead of clamped --
// the clamp re-loaded the final window pair up to 3x (+12.5% read traffic).
// Warmup load is a normal (cacheable) load: it overlaps the previous
// segment's payload, so it may hit L2.

#define B_ 8
#define C_ 512
#define T_ 16384
#define SEGS 4
#define SEGV (T_ / SEGS / 4)    // 1024 float4 per segment
#define NITER (SEGV / 128)      // 8 iterations (128 float4 / wave / iter)

typedef float f4 __attribute__((ext_vector_type(4)));

__global__ __launch_bounds__(256)
void ema_scan_kernel(const float* __restrict__ x,
                     const float* __restrict__ weight,
                     float* __restrict__ out) {
    const int tid  = threadIdx.x;
    const int lane = tid & 63;
    const int w    = tid >> 6;                  // wave id in block
    const int gid  = (blockIdx.x << 2) + w;     // 0..16383
    const int row  = gid >> 2;                  // 0..4095  (b*C + c)
    const int seg  = gid & 3;                   // 0..3
    const int c    = row & (C_ - 1);

    const float g     = weight[c];
    const float onemg = 1.0f - g;

    // powers of g: f[k] = g^(4*2^k)  (g^4 .. g^128)
    const float g2 = g * g;
    const float g4 = g2 * g2;
    float f[6];
    f[0] = g4;
    #pragma unroll
    for (int k = 1; k < 6; ++k) f[k] = f[k - 1] * f[k - 1];
    const float g256 = f[5] * f[5];             // half-window carry factor
    // lane_factor = g^(4*lane); rev_factor = g^(4*(63-lane))
    float lane_factor = 1.0f, rev_factor = 1.0f;
    #pragma unroll
    for (int k = 0; k < 6; ++k) {
        if (lane & (1 << k))        lane_factor *= f[k];
        if ((lane ^ 63) & (1 << k)) rev_factor  *= f[k];
    }

    const f4* __restrict__ xrow = (const f4*)(x   + (size_t)row * T_);
    f4*       __restrict__ orow = (f4*)      (out + (size_t)row * T_);

    const int segv0 = seg * SEGV;               // first float4 index of segment

    // ---- warmup: incoming carry from the 256 elems before the segment ----
    float carry = 0.0f;
    if (seg != 0) {
        const f4 Xw = xrow[segv0 - 64 + lane];  // cacheable: overlaps seg-1 payload
        // p = g^3*Xw.x + g^2*Xw.y + g*Xw.z + Xw.w
        const float p = fmaf(g, fmaf(g, fmaf(g, Xw.x, Xw.y), Xw.z), Xw.w);
        float t = rev_factor * p;
        #pragma unroll
        for (int k = 0; k < 6; ++k)
            t += __shfl_xor(t, 1 << k, 64);     // butterfly: all lanes get sum
        carry = onemg * t;                      // = y[segment_start - 1]
    }

    // ---- depth-2 pipelined main scan, 512 elems (two half-windows) / iter ----
    f4 XA0 = __builtin_nontemporal_load(&xrow[segv0 + lane]);
    f4 XB0 = __builtin_nontemporal_load(&xrow[segv0 + 64 + lane]);
    f4 XA1 = __builtin_nontemporal_load(&xrow[segv0 + 128 + lane]);
    f4 XB1 = __builtin_nontemporal_load(&xrow[segv0 + 192 + lane]);

    #pragma unroll 2
    for (int it = 0; it < NITER; ++it) {
        f4 XAn = {0.f, 0.f, 0.f, 0.f};
        f4 XBn = {0.f, 0.f, 0.f, 0.f};
        if (it + 2 < NITER) {                   // uniform branch: each pair
            XAn = __builtin_nontemporal_load(&xrow[segv0 + (it + 2) * 128 + lane]);
            XBn = __builtin_nontemporal_load(&xrow[segv0 + (it + 2) * 128 + 64 + lane]);
        }

        // local 4-element scans (zero carry-in), two independent chains
        const float a0 = onemg * XA0.x;
        const float b0 = onemg * XB0.x;
        const float a1 = fmaf(g, a0, onemg * XA0.y);
        const float b1 = fmaf(g, b0, onemg * XB0.y);
        const float a2 = fmaf(g, a1, onemg * XA0.z);
        const float b2 = fmaf(g, b1, onemg * XB0.z);
        const float a3 = fmaf(g, a2, onemg * XA0.w);
        const float b3 = fmaf(g, b2, onemg * XB0.w);

        // Kogge-Stone inclusive scans of per-lane carries (factor g^4), ILP=2
        float vA = a3, vB = b3;
        #pragma unroll
        for (int k = 0; k < 6; ++k) {
            const float tA = __shfl_up(vA, 1 << k, 64);
            const float tB = __shfl_up(vB, 1 << k, 64);
            if (lane >= (1 << k)) {
                vA = fmaf(f[k], tA, vA);
                vB = fmaf(f[k], tB, vB);
            }
        }
        float eA = __shfl_up(vA, 1, 64);
        float eB = __shfl_up(vB, 1, 64);
        if (lane == 0) { eA = 0.0f; eB = 0.0f; }
        const float vA63 = __shfl(vA, 63, 64);
        const float vB63 = __shfl(vB, 63, 64);

        // absolute carries just before this thread's elements, each half
        const float cA  = fmaf(lane_factor, carry, eA);
        const float mid = fmaf(g256, carry, vA63);       // y before B-half
        const float cB  = fmaf(lane_factor, mid, eB);

        float gpA = g * cA;
        float gpB = g * cB;
        f4 YA, YB;
        YA.x = a0 + gpA; gpA *= g;
        YB.x = b0 + gpB; gpB *= g;
        YA.y = a1 + gpA; gpA *= g;
        YB.y = b1 + gpB; gpB *= g;
        YA.z = a2 + gpA; gpA *= g;
        YB.z = b2 + gpB; gpB *= g;
        YA.w = a3 + gpA;
        YB.w = b3 + gpB;
        __builtin_nontemporal_store(YA, &orow[segv0 + it * 128 + lane]);
        __builtin_nontemporal_store(YB, &orow[segv0 + it * 128 + 64 + lane]);

        carry = fmaf(g256, mid, vB63);          // exact cross-window carry
        XA0 = XA1; XB0 = XB1; XA1 = XAn; XB1 = XBn;
    }
}

extern "C" void kernel_launch(void* const* d_in, const int* in_sizes, int n_in,
                              void* d_out, int out_size, void* d_ws, size_t ws_size,
                              hipStream_t stream) {
    const float* x      = (const float*)d_in[0];
    const float* weight = (const float*)d_in[1];
    float* out          = (float*)d_out;
    ema_scan_kernel<<<(B_ * C_ * SEGS) / 4, 256, 0, stream>>>(x, weight, out);
}